// Round 13
// baseline (1100.592 us; speedup 1.0000x reference)
//
#include <hip/hip_runtime.h>
#include <cstdint>
#include <cstddef>

// Problem constants
#define HD 1024               // hidden
#define FF 4096               // ffn
#define TOK 8192              // 4*2048 tokens
#define NSEG 9                // 8 routed experts + 1 shared (segment 8)
#define ROWS_ROUTED (TOK*2)   // exactly K=2 assignments per token
#define ROWS_TOT (ROWS_ROUTED + TOK)

typedef __bf16 bf16;
typedef __bf16 bf16x8 __attribute__((ext_vector_type(8)));
typedef __bf16 bf16x4 __attribute__((ext_vector_type(4)));
typedef float  f32x4  __attribute__((ext_vector_type(4)));

__device__ __forceinline__ void stage16(const void* g, void* l) {
  __builtin_amdgcn_global_load_lds((const __attribute__((address_space(1))) void*)g,
                                   (__attribute__((address_space(3))) void*)l,
                                   16, 0, 0);
}

__device__ __forceinline__ unsigned short bf_bits(float v) {
  bf16 b = (bf16)v;
  return __builtin_bit_cast(unsigned short, b);
}

// fast gelu (sigmoid form); ~1e-3 abs dev, negligible vs 0.123 threshold.
__device__ __forceinline__ float fast_gelu(float v) {
  float u = 1.595769122f * v * (1.0f + 0.044715f * v * v);
  float s = 1.0f / (1.0f + __expf(-u));
  return v * s;
}

// XCD co-location: runs of 8 consecutive LOGICAL blocks (sharing an A-strip)
// land on dispatch slots with identical d%8. Bijective when gridDim.x%64==0.
__device__ __forceinline__ int xcd_remap(int d) {
  return (((d >> 6) << 3) + (d & 7)) * 8 + ((d >> 3) & 7);
}

// meta layout (ints): [0..7] cnt, [8..15] cnt2, [16..24] segoff, [32..40] segrows

// merged transpose+convert for BOTH weight sets
__global__ void k_tcvt(const float* __restrict__ routed_up, const float* __restrict__ shared_up,
                       const float* __restrict__ routed_dn, const float* __restrict__ shared_dn,
                       bf16* __restrict__ wupT, bf16* __restrict__ wdnT) {
  int z = blockIdx.z;
  bool isup = z < 9;
  int e = isup ? z : z - 9;
  const float* src = isup ? ((e < 8) ? (routed_up + (size_t)e*HD*FF) : shared_up)
                          : ((e < 8) ? (routed_dn + (size_t)e*FF*HD) : shared_dn);
  bf16* d = (isup ? wupT : wdnT) + (size_t)e*FF*HD;
  int R = isup ? HD : FF, C = isup ? FF : HD;
  int r0 = (isup ? blockIdx.y : blockIdx.x) * 64;
  int c0 = (isup ? blockIdx.x : blockIdx.y) * 64;
  __shared__ float lds[64][65];
  int t = threadIdx.x;
  int tr = t>>4, tc4 = (t&15)*4;
  #pragma unroll
  for (int i=0;i<4;i++) {
    float4 v = *reinterpret_cast<const float4*>(src + (size_t)(r0+tr+i*16)*C + c0 + tc4);
    lds[tr+i*16][tc4+0]=v.x; lds[tr+i*16][tc4+1]=v.y;
    lds[tr+i*16][tc4+2]=v.z; lds[tr+i*16][tc4+3]=v.w;
  }
  __syncthreads();
  #pragma unroll
  for (int i=0;i<4;i++) {
    int oc = tr + i*16;
    ushort4 u;
    u.x = bf_bits(lds[tc4+0][oc]);
    u.y = bf_bits(lds[tc4+1][oc]);
    u.z = bf_bits(lds[tc4+2][oc]);
    u.w = bf_bits(lds[tc4+3][oc]);
    *reinterpret_cast<ushort4*>(d + (size_t)(c0+oc)*R + r0 + tc4) = u;
  }
}

// fp32 router (+ fused x->bf16 conversion): one wave per token.
__global__ void k_router(const float* __restrict__ x, const float* __restrict__ rw,
                         bf16* __restrict__ xbf,
                         int* __restrict__ rtE, float* __restrict__ rtG,
                         int* __restrict__ meta) {
  __shared__ float rwl[HD*8];
  int t = threadIdx.x;
  for (int i=t;i<HD*8/4;i+=256)
    reinterpret_cast<float4*>(rwl)[i] = reinterpret_cast<const float4*>(rw)[i];
  __syncthreads();
  int wv = t>>6, lane = t&63;
  int tk = blockIdx.x*4 + wv;
  const float* xr = x + (size_t)tk*HD;
  bf16* xb = xbf + (size_t)tk*HD;
  float a[8] = {0,0,0,0,0,0,0,0};
  for (int i=0;i<HD/64;i++) {
    int h = lane + i*64;
    float xv = xr[h];
    xb[h] = (bf16)xv;
    const float* r = rwl + h*8;
    #pragma unroll
    for (int e=0;e<8;e++) a[e] = fmaf(xv, r[e], a[e]);
  }
  #pragma unroll
  for (int e=0;e<8;e++) {
    for (int s=32;s>0;s>>=1) a[e] += __shfl_xor(a[e], s, 64);
  }
  if (lane==0) {
    float mx = a[0];
    #pragma unroll
    for (int e=1;e<8;e++) mx = fmaxf(mx, a[e]);
    float p[8]; float den = 0.f;
    #pragma unroll
    for (int e=0;e<8;e++) { p[e] = expf(a[e]-mx); den += p[e]; }
    int i0 = 0;
    #pragma unroll
    for (int e=1;e<8;e++) if (p[e] > p[i0]) i0 = e;
    int i1 = (i0==0)?1:0;
    #pragma unroll
    for (int e=0;e<8;e++) if (e!=i0 && p[e] > p[i1]) i1 = e;
    float inv = 1.f/den;
    rtE[tk*2] = i0; rtE[tk*2+1] = i1;
    rtG[tk*2] = p[i0]*inv; rtG[tk*2+1] = p[i1]*inv;
    atomicAdd(&meta[i0], 1);
    atomicAdd(&meta[i1], 1);
  }
}

// scatter with LOCAL prefix; block 0 publishes segoff/rows
__global__ void k_scatter(const int* __restrict__ rtE, const float* __restrict__ rtG,
                          int* __restrict__ meta, int* __restrict__ tok,
                          float* __restrict__ gate, int* __restrict__ trow) {
  __shared__ int soff[8];
  int t = threadIdx.x;
  if (t == 0) {
    int off = 0;
    #pragma unroll
    for (int e=0;e<8;e++) { soff[e] = off; off += meta[e]; }
    if (blockIdx.x == 0) {
      int o2 = 0;
      #pragma unroll
      for (int e=0;e<8;e++) { meta[16+e] = o2; meta[32+e] = meta[e]; o2 += meta[e]; }
      meta[16+8] = ROWS_ROUTED;
      meta[32+8] = TOK;
    }
  }
  __syncthreads();
  int tk = blockIdx.x*256 + t;
  int e0 = rtE[tk*2], e1 = rtE[tk*2+1];
  float g0 = rtG[tk*2], g1 = rtG[tk*2+1];
  int p0 = atomicAdd(&meta[8+e0], 1);
  int r0 = soff[e0] + p0;
  tok[r0] = tk; gate[r0] = g0; trow[tk*2] = r0;
  int p1 = atomicAdd(&meta[8+e1], 1);
  int r1 = soff[e1] + p1;
  tok[r1] = tk; gate[r1] = g1; trow[tk*2+1] = r1;
  tok[ROWS_ROUTED + tk] = tk; gate[ROWS_ROUTED + tk] = 1.0f;
}

// final combine: out[t] = x[t] + shared_row(t) + routed_row0(t) + routed_row1(t)
__global__ void k_combine(const float* __restrict__ x, const bf16* __restrict__ dbuf,
                          const int* __restrict__ trow, float* __restrict__ out) {
  int tkn = blockIdx.x;
  int t = threadIdx.x;
  int r0 = trow[tkn*2], r1 = trow[tkn*2+1];
  int h = t*4;
  float4 xv = *reinterpret_cast<const float4*>(x + (size_t)tkn*HD + h);
  bf16x4 a = *reinterpret_cast<const bf16x4*>(dbuf + (size_t)(ROWS_ROUTED+tkn)*HD + h);
  bf16x4 b = *reinterpret_cast<const bf16x4*>(dbuf + (size_t)r0*HD + h);
  bf16x4 c = *reinterpret_cast<const bf16x4*>(dbuf + (size_t)r1*HD + h);
  float4 o;
  o.x = xv.x + (float)a[0] + (float)b[0] + (float)c[0];
  o.y = xv.y + (float)a[1] + (float)b[1] + (float)c[1];
  o.z = xv.z + (float)a[2] + (float)b[2] + (float)c[2];
  o.w = xv.w + (float)a[3] + (float)b[3] + (float)c[3];
  *reinterpret_cast<float4*>(out + (size_t)tkn*HD + h) = o;
}

// ======== phase-split grouped GEMMs: BM=256 x BN=128 x BK=64, 512 thr ========
// 8 waves (2M x 4N): wave owns 128x32 output. 3 K-tile LDS dbufs (48KB each,
// 144KB total -> 1 block/CU): dbuf d = [A: [ks][256][32]bf16, A[ks]@ks*16384]
// [B: [ks][128][32], B[ks]@32768+ks*8192].   (R12 BUG was B stride 16384 ->
// ks=1 slab overwrote the next dbuf's A region / ran past the LDS array.)
// 64B rows -> verified slot-XOR swizzle unchanged (content(row,slot) = chunk
// slot^((row>>1)&3), via pre-swizzled GLOBAL src; row bits 1-2 come only from
// lane&15 in all fragment reads).
// Per K-tile: 4 phases (ks,qm): {6 ds_read; 2 stage; s_barrier; setprio(1);
// 8 MFMA; setprio(0); s_barrier}. Tile kt stages tile kt+2 into dbuf (db+2)%3
// (read last at iter kt-1, sealed by that iter's boundary barrier). Boundary:
// vmcnt(6) drains exactly tile kt+1's 6 loads, leaves kt+2's 6 in flight.
// Induction: at boundary of tile j, outstanding = {j+1's 6 old, j+2's 6 new};
// base: prologue stages t0,t1 (12) then vmcnt(6) drains t0's.

#define DBUF 49152

#define GEMM_PH(cb, ks, qm, STAGES) { \
    bf16x8 a0 = *reinterpret_cast<const bf16x8*>((cb) + (ks)*16384 + ((qm)*64+ 0)*64 + AfB); \
    bf16x8 a1 = *reinterpret_cast<const bf16x8*>((cb) + (ks)*16384 + ((qm)*64+16)*64 + AfB); \
    bf16x8 a2 = *reinterpret_cast<const bf16x8*>((cb) + (ks)*16384 + ((qm)*64+32)*64 + AfB); \
    bf16x8 a3 = *reinterpret_cast<const bf16x8*>((cb) + (ks)*16384 + ((qm)*64+48)*64 + AfB); \
    bf16x8 b0 = *reinterpret_cast<const bf16x8*>((cb) + 32768 + (ks)*8192 + BfB); \
    bf16x8 b1 = *reinterpret_cast<const bf16x8*>((cb) + 32768 + (ks)*8192 + 1024 + BfB); \
    STAGES; \
    __builtin_amdgcn_s_barrier(); \
    __builtin_amdgcn_s_setprio(1); \
    acc[(qm)*4+0][0] = __builtin_amdgcn_mfma_f32_16x16x32_bf16(b0,a0,acc[(qm)*4+0][0],0,0,0); \
    acc[(qm)*4+1][0] = __builtin_amdgcn_mfma_f32_16x16x32_bf16(b0,a1,acc[(qm)*4+1][0],0,0,0); \
    acc[(qm)*4+2][0] = __builtin_amdgcn_mfma_f32_16x16x32_bf16(b0,a2,acc[(qm)*4+2][0],0,0,0); \
    acc[(qm)*4+3][0] = __builtin_amdgcn_mfma_f32_16x16x32_bf16(b0,a3,acc[(qm)*4+3][0],0,0,0); \
    acc[(qm)*4+0][1] = __builtin_amdgcn_mfma_f32_16x16x32_bf16(b1,a0,acc[(qm)*4+0][1],0,0,0); \
    acc[(qm)*4+1][1] = __builtin_amdgcn_mfma_f32_16x16x32_bf16(b1,a1,acc[(qm)*4+1][1],0,0,0); \
    acc[(qm)*4+2][1] = __builtin_amdgcn_mfma_f32_16x16x32_bf16(b1,a2,acc[(qm)*4+2][1],0,0,0); \
    acc[(qm)*4+3][1] = __builtin_amdgcn_mfma_f32_16x16x32_bf16(b1,a3,acc[(qm)*4+3][1],0,0,0); \
    __builtin_amdgcn_s_setprio(0); \
  }

// stage unit macros: A unit (ks,rh) and B unit (ks) of K-tile kt into buffer nb
#define STG_A(kt, nb, ks, rh) stage16(((rh)? gA1 : gA0) + (kt)*64 + (ks)*32, (nb) + (ks)*16384 + (rh)*8192 + dstT)
#define STG_B(kt, nb, ks)     stage16(gB + (kt)*64 + (ks)*32, (nb) + 32768 + (ks)*8192 + dstT)

__global__ __launch_bounds__(512,2) void k_gemm_up(
    const bf16* __restrict__ xbf, const bf16* __restrict__ wupT,
    bf16* __restrict__ hbuf, const int* __restrict__ tok,
    const int* __restrict__ meta)
{
  int bx = xcd_remap(blockIdx.x);
  int seg = bx >> 10;           // 32 mt * 32 nt per segment
  int rem = bx & 1023;
  int mt = rem >> 5, nt = rem & 31;   // nt fastest
  int rows = (seg<8)? meta[32+seg] : TOK;
  if (mt*256 >= rows) return;
  int segoff = meta[16+seg];
  int rowbase = mt*256;

  __shared__ __align__(16) char lds[3*DBUF];

  const int t = threadIdx.x;
  const int lane = t & 63, w = t >> 6;
  const int wm = w >> 2, wn = w & 3;

  int kswz = ((t&3) ^ ((t>>3)&3)) * 8;
  int g0 = rowbase + (t>>2);       if (g0 >= rows) g0 = rows-1;
  int g1 = rowbase + 128 + (t>>2); if (g1 >= rows) g1 = rows-1;
  const bf16* gA0 = xbf + (size_t)tok[segoff+g0]*HD + kswz;
  const bf16* gA1 = xbf + (size_t)tok[segoff+g1]*HD + kswz;
  const bf16* gB  = wupT + (size_t)seg*FF*HD + (size_t)(nt*128 + (t>>2))*HD + kswz;
  const int dstT = t*16;

  const int slotb = ((lane>>4) ^ (((lane&15)>>1)&3)) * 16;
  const int AfB = (wm*128 + (lane&15))*64 + slotb;
  const int BfB = (wn*32 + (lane&15))*64 + slotb;

  f32x4 acc[8][2] = {};

  // prologue: tile0 -> dbuf0, tile1 -> dbuf1
  {
    char* nb = lds;
    STG_A(0,nb,0,0); STG_A(0,nb,0,1); STG_A(0,nb,1,0); STG_A(0,nb,1,1);
    STG_B(0,nb,0); STG_B(0,nb,1);
    nb = lds + DBUF;
    STG_A(1,nb,0,0); STG_A(1,nb,0,1); STG_A(1,nb,1,0); STG_A(1,nb,1,1);
    STG_B(1,nb,0); STG_B(1,nb,1);
  }
  asm volatile("s_waitcnt vmcnt(6)" ::: "memory");
  __builtin_amdgcn_s_barrier();

  const int NT = HD/64;  // 16
  int db = 0;
  for (int kt = 0; kt < NT; ++kt) {
    char* cb = lds + db*DBUF;
    int dn = db + 2; if (dn >= 3) dn -= 3;
    char* nb = lds + dn*DBUF;
    bool pf = (kt + 2 < NT);

    GEMM_PH(cb, 0, 0, if(pf){ STG_A(kt+2,nb,0,0); STG_A(kt+2,nb,0,1); });
    __builtin_amdgcn_s_barrier();
    GEMM_PH(cb, 1, 0, if(pf){ STG_A(kt+2,nb,1,0); STG_A(kt+2,nb,1,1); });
    __builtin_amdgcn_s_barrier();
    GEMM_PH(cb, 0, 1, if(pf){ STG_B(kt+2,nb,0); STG_B(kt+2,nb,1); });
    __builtin_amdgcn_s_barrier();
    GEMM_PH(cb, 1, 1, );
    if (kt + 1 < NT) {
      if (pf) asm volatile("s_waitcnt vmcnt(6)" ::: "memory");
      else    asm volatile("s_waitcnt vmcnt(0)" ::: "memory");
      __builtin_amdgcn_s_barrier();
    }
    db += 1; if (db >= 3) db = 0;
  }

  // epilogue: fast gelu -> packed 8B stores
  const int lrm = lane&15, lq = lane>>4;
  #pragma unroll
  for (int m=0;m<8;m++) {
    int rl = wm*128 + m*16 + lrm;
    int gr = rowbase + rl;
    if (gr >= rows) continue;
    bf16* hrow = hbuf + (size_t)(segoff+gr)*FF + nt*128 + wn*32 + lq*4;
    #pragma unroll
    for (int n=0;n<2;n++) {
      bf16x4 u;
      #pragma unroll
      for (int j=0;j<4;j++) u[j] = (bf16)fast_gelu(acc[m][n][j]);
      *reinterpret_cast<bf16x4*>(hrow + n*16) = u;
    }
  }
}

__global__ __launch_bounds__(512,2) void k_gemm_down(
    const bf16* __restrict__ hbuf, const bf16* __restrict__ wdnT,
    bf16* __restrict__ dbuf, const float* __restrict__ gate,
    const int* __restrict__ meta)
{
  int bx = xcd_remap(blockIdx.x);
  int seg = bx >> 8;            // 32 mt * 8 nt per segment
  int rem = bx & 255;
  int mt = rem >> 3, nt = rem & 7;   // nt fastest
  int rows = (seg<8)? meta[32+seg] : TOK;
  if (mt*256 >= rows) return;
  int segoff = meta[16+seg];
  int rowbase = mt*256;

  __shared__ __align__(16) char lds[3*DBUF];
  __shared__ float gateL[256];

  const int t = threadIdx.x;
  const int lane = t & 63, w = t >> 6;
  const int wm = w >> 2, wn = w & 3;

  if (t < 256) {
    int gr = rowbase + t; if (gr >= rows) gr = rows - 1;
    gateL[t] = gate[segoff + gr];
  }

  int kswz = ((t&3) ^ ((t>>3)&3)) * 8;
  int g0 = rowbase + (t>>2);       if (g0 >= rows) g0 = rows-1;
  int g1 = rowbase + 128 + (t>>2); if (g1 >= rows) g1 = rows-1;
  const bf16* gA0 = hbuf + (size_t)(segoff+g0)*FF + kswz;
  const bf16* gA1 = hbuf + (size_t)(segoff+g1)*FF + kswz;
  const bf16* gB  = wdnT + (size_t)seg*HD*FF + (size_t)(nt*128 + (t>>2))*FF + kswz;
  const int dstT = t*16;

  const int slotb = ((lane>>4) ^ (((lane&15)>>1)&3)) * 16;
  const int AfB = (wm*128 + (lane&15))*64 + slotb;
  const int BfB = (wn*32 + (lane&15))*64 + slotb;

  f32x4 acc[8][2] = {};

  {
    char* nb = lds;
    STG_A(0,nb,0,0); STG_A(0,nb,0,1); STG_A(0,nb,1,0); STG_A(0,nb,1,1);
    STG_B(0,nb,0); STG_B(0,nb,1);
    nb = lds + DBUF;
    STG_A(1,nb,0,0); STG_A(1,nb,0,1); STG_A(1,nb,1,0); STG_A(1,nb,1,1);
    STG_B(1,nb,0); STG_B(1,nb,1);
  }
  asm volatile("s_waitcnt vmcnt(6)" ::: "memory");
  __builtin_amdgcn_s_barrier();

  const int NT = FF/64;  // 64
  int db = 0;
  for (int kt = 0; kt < NT; ++kt) {
    char* cb = lds + db*DBUF;
    int dn = db + 2; if (dn >= 3) dn -= 3;
    char* nb = lds + dn*DBUF;
    bool pf = (kt + 2 < NT);

    GEMM_PH(cb, 0, 0, if(pf){ STG_A(kt+2,nb,0,0); STG_A(kt+2,nb,0,1); });
    __builtin_amdgcn_s_barrier();
    GEMM_PH(cb, 1, 0, if(pf){ STG_A(kt+2,nb,1,0); STG_A(kt+2,nb,1,1); });
    __builtin_amdgcn_s_barrier();
    GEMM_PH(cb, 0, 1, if(pf){ STG_B(kt+2,nb,0); STG_B(kt+2,nb,1); });
    __builtin_amdgcn_s_barrier();
    GEMM_PH(cb, 1, 1, );
    if (kt + 1 < NT) {
      if (pf) asm volatile("s_waitcnt vmcnt(6)" ::: "memory");
      else    asm volatile("s_waitcnt vmcnt(0)" ::: "memory");
      __builtin_amdgcn_s_barrier();
    }
    db += 1; if (db >= 3) db = 0;
  }

  // epilogue: gate * val -> dbuf rows (bf16, 8B packed)
  const int lrm = lane&15, lq = lane>>4;
  #pragma unroll
  for (int m=0;m<8;m++) {
    int rl = wm*128 + m*16 + lrm;
    int gr = rowbase + rl;
    if (gr >= rows) continue;
    float g = gateL[rl];
    bf16* drow = dbuf + (size_t)(segoff+gr)*HD + nt*128 + wn*32 + lq*4;
    #pragma unroll
    for (int n=0;n<2;n++) {
      bf16x4 u;
      #pragma unroll
      for (int j=0;j<4;j++) u[j] = (bf16)(acc[m][n][j]*g);
      *reinterpret_cast<bf16x4*>(drow + n*16) = u;
    }
  }
}

// ---------------- host ----------------
struct Layout {
  size_t xbf, wupT, wdnT, hbuf, dbuf, tok, gate, trow, rtE, rtG, meta, total;
};

static inline Layout make_layout() {
  Layout L; size_t o = 0;
  auto al = [&](size_t b){ o = (o+255)&~(size_t)255; size_t r=o; o+=b; return r; };
  L.xbf  = al((size_t)TOK*HD*2);
  L.wupT = al((size_t)NSEG*FF*HD*2);
  L.wdnT = al((size_t)NSEG*FF*HD*2);
  L.hbuf = al((size_t)ROWS_TOT*FF*2);
  L.dbuf = al((size_t)ROWS_TOT*HD*2);
  L.tok  = al((size_t)ROWS_TOT*4);
  L.gate = al((size_t)ROWS_TOT*4);
  L.trow = al((size_t)TOK*2*4);
  L.rtE  = al((size_t)TOK*2*4);
  L.rtG  = al((size_t)TOK*2*4);
  L.meta = al(256*4);
  L.total = o;
  return L;
}

extern "C" void kernel_launch(void* const* d_in, const int* in_sizes, int n_in,
                              void* d_out, int out_size, void* d_ws, size_t ws_size,
                              hipStream_t stream) {
  const float* x           = (const float*)d_in[0];
  const float* shared_up   = (const float*)d_in[1];
  const float* shared_down = (const float*)d_in[2];
  const float* routed_up   = (const float*)d_in[3];
  const float* routed_down = (const float*)d_in[4];
  const float* router_w    = (const float*)d_in[5];
  float* out = (float*)d_out;

  Layout L = make_layout();
  char* ws = (char*)d_ws;
  bf16*  xbf  = (bf16*)(ws + L.xbf);
  bf16*  wupT = (bf16*)(ws + L.wupT);
  bf16*  wdnT = (bf16*)(ws + L.wdnT);
  bf16*  hbuf = (bf16*)(ws + L.hbuf);
  bf16*  dbuf = (bf16*)(ws + L.dbuf);
  int*   tok  = (int*)(ws + L.tok);
  float* gate = (float*)(ws + L.gate);
  int*   trow = (int*)(ws + L.trow);
  int*   rtE  = (int*)(ws + L.rtE);
  float* rtG  = (float*)(ws + L.rtG);
  int*   meta = (int*)(ws + L.meta);

  hipMemsetAsync(meta, 0, 256*4, stream);
  k_tcvt<<<dim3(64, 16, 18), 256, 0, stream>>>(routed_up, shared_up, routed_down, shared_down, wupT, wdnT);
  k_router<<<TOK/4, 256, 0, stream>>>(x, router_w, xbf, rtE, rtG, meta);
  k_scatter<<<TOK/256, 256, 0, stream>>>(rtE, rtG, meta, tok, gate, trow);

  k_gemm_up<<<NSEG*32*32, 512, 0, stream>>>(xbf, wupT, hbuf, tok, meta);      // 9216 blocks
  k_gemm_down<<<NSEG*32*8, 512, 0, stream>>>(hbuf, wdnT, dbuf, gate, meta);   // 2304 blocks
  k_combine<<<TOK, 256, 0, stream>>>(x, dbuf, trow, out);
}

// Round 14
// 956.247 us; speedup vs baseline: 1.1509x; 1.1509x over previous
//
#include <hip/hip_runtime.h>
#include <cstdint>
#include <cstddef>

// Problem constants
#define HD 1024               // hidden
#define FF 4096               // ffn
#define TOK 8192              // 4*2048 tokens
#define NSEG 9                // 8 routed experts + 1 shared (segment 8)
#define ROWS_ROUTED (TOK*2)   // exactly K=2 assignments per token
#define ROWS_TOT (ROWS_ROUTED + TOK)

typedef __bf16 bf16;
typedef __bf16 bf16x8 __attribute__((ext_vector_type(8)));
typedef __bf16 bf16x4 __attribute__((ext_vector_type(4)));
typedef float  f32x4  __attribute__((ext_vector_type(4)));

__device__ __forceinline__ void stage16(const void* g, void* l) {
  __builtin_amdgcn_global_load_lds((const __attribute__((address_space(1))) void*)g,
                                   (__attribute__((address_space(3))) void*)l,
                                   16, 0, 0);
}

__device__ __forceinline__ unsigned short bf_bits(float v) {
  bf16 b = (bf16)v;
  return __builtin_bit_cast(unsigned short, b);
}

// fast gelu: sigmoid form of the tanh approximation.
// gelu(v) ~= v * sigmoid(1.595769122*(v + 0.044715*v^3)); max abs dev ~1e-3,
// negligible vs the 0.123 abs threshold (bf16 path already at 0.031).
__device__ __forceinline__ float fast_gelu(float v) {
  float u = 1.595769122f * v * (1.0f + 0.044715f * v * v);
  float s = 1.0f / (1.0f + __expf(-u));
  return v * s;
}

// XCD co-location: runs of 8 consecutive LOGICAL blocks (sharing an A-strip)
// land on dispatch slots with identical d%8 (= same XCD under round-robin).
// Bijective when gridDim.x % 64 == 0.
__device__ __forceinline__ int xcd_remap(int d) {
  return (((d >> 6) << 3) + (d & 7)) * 8 + ((d >> 3) & 7);
}

// meta layout (ints): [0..7] cnt, [8..15] cnt2, [16..24] segoff, [32..40] segrows
// (meta zeroed host-side via hipMemsetAsync)

// merged transpose+convert for BOTH weight sets:
// z<9: up (src [HD][FF], dst [FF][HD]); z>=9: down (src [FF][HD], dst [HD][FF])
__global__ void k_tcvt(const float* __restrict__ routed_up, const float* __restrict__ shared_up,
                       const float* __restrict__ routed_dn, const float* __restrict__ shared_dn,
                       bf16* __restrict__ wupT, bf16* __restrict__ wdnT) {
  int z = blockIdx.z;
  bool isup = z < 9;
  int e = isup ? z : z - 9;
  const float* src = isup ? ((e < 8) ? (routed_up + (size_t)e*HD*FF) : shared_up)
                          : ((e < 8) ? (routed_dn + (size_t)e*FF*HD) : shared_dn);
  bf16* d = (isup ? wupT : wdnT) + (size_t)e*FF*HD;
  int R = isup ? HD : FF, C = isup ? FF : HD;
  int r0 = (isup ? blockIdx.y : blockIdx.x) * 64;
  int c0 = (isup ? blockIdx.x : blockIdx.y) * 64;
  __shared__ float lds[64][65];
  int t = threadIdx.x;
  int tr = t>>4, tc4 = (t&15)*4;
  #pragma unroll
  for (int i=0;i<4;i++) {
    float4 v = *reinterpret_cast<const float4*>(src + (size_t)(r0+tr+i*16)*C + c0 + tc4);
    lds[tr+i*16][tc4+0]=v.x; lds[tr+i*16][tc4+1]=v.y;
    lds[tr+i*16][tc4+2]=v.z; lds[tr+i*16][tc4+3]=v.w;
  }
  __syncthreads();
  #pragma unroll
  for (int i=0;i<4;i++) {
    int oc = tr + i*16;
    ushort4 u;
    u.x = bf_bits(lds[tc4+0][oc]);
    u.y = bf_bits(lds[tc4+1][oc]);
    u.z = bf_bits(lds[tc4+2][oc]);
    u.w = bf_bits(lds[tc4+3][oc]);
    *reinterpret_cast<ushort4*>(d + (size_t)(c0+oc)*R + r0 + tc4) = u;
  }
}

// fp32 router (+ fused x->bf16 conversion): one wave per token.
__global__ void k_router(const float* __restrict__ x, const float* __restrict__ rw,
                         bf16* __restrict__ xbf,
                         int* __restrict__ rtE, float* __restrict__ rtG,
                         int* __restrict__ meta) {
  __shared__ float rwl[HD*8];
  int t = threadIdx.x;
  for (int i=t;i<HD*8/4;i+=256)
    reinterpret_cast<float4*>(rwl)[i] = reinterpret_cast<const float4*>(rw)[i];
  __syncthreads();
  int wv = t>>6, lane = t&63;
  int tk = blockIdx.x*4 + wv;
  const float* xr = x + (size_t)tk*HD;
  bf16* xb = xbf + (size_t)tk*HD;
  float a[8] = {0,0,0,0,0,0,0,0};
  for (int i=0;i<HD/64;i++) {
    int h = lane + i*64;
    float xv = xr[h];
    xb[h] = (bf16)xv;
    const float* r = rwl + h*8;
    #pragma unroll
    for (int e=0;e<8;e++) a[e] = fmaf(xv, r[e], a[e]);
  }
  #pragma unroll
  for (int e=0;e<8;e++) {
    for (int s=32;s>0;s>>=1) a[e] += __shfl_xor(a[e], s, 64);
  }
  if (lane==0) {
    float mx = a[0];
    #pragma unroll
    for (int e=1;e<8;e++) mx = fmaxf(mx, a[e]);
    float p[8]; float den = 0.f;
    #pragma unroll
    for (int e=0;e<8;e++) { p[e] = expf(a[e]-mx); den += p[e]; }
    int i0 = 0;
    #pragma unroll
    for (int e=1;e<8;e++) if (p[e] > p[i0]) i0 = e;
    int i1 = (i0==0)?1:0;
    #pragma unroll
    for (int e=0;e<8;e++) if (e!=i0 && p[e] > p[i1]) i1 = e;
    float inv = 1.f/den;
    rtE[tk*2] = i0; rtE[tk*2+1] = i1;
    rtG[tk*2] = p[i0]*inv; rtG[tk*2+1] = p[i1]*inv;
    atomicAdd(&meta[i0], 1);
    atomicAdd(&meta[i1], 1);
  }
}

// scatter with LOCAL prefix; block 0 publishes segoff/rows
__global__ void k_scatter(const int* __restrict__ rtE, const float* __restrict__ rtG,
                          int* __restrict__ meta, int* __restrict__ tok,
                          float* __restrict__ gate, int* __restrict__ trow) {
  __shared__ int soff[8];
  int t = threadIdx.x;
  if (t == 0) {
    int off = 0;
    #pragma unroll
    for (int e=0;e<8;e++) { soff[e] = off; off += meta[e]; }
    if (blockIdx.x == 0) {
      int o2 = 0;
      #pragma unroll
      for (int e=0;e<8;e++) { meta[16+e] = o2; meta[32+e] = meta[e]; o2 += meta[e]; }
      meta[16+8] = ROWS_ROUTED;
      meta[32+8] = TOK;
    }
  }
  __syncthreads();
  int tk = blockIdx.x*256 + t;
  int e0 = rtE[tk*2], e1 = rtE[tk*2+1];
  float g0 = rtG[tk*2], g1 = rtG[tk*2+1];
  int p0 = atomicAdd(&meta[8+e0], 1);
  int r0 = soff[e0] + p0;
  tok[r0] = tk; gate[r0] = g0; trow[tk*2] = r0;
  int p1 = atomicAdd(&meta[8+e1], 1);
  int r1 = soff[e1] + p1;
  tok[r1] = tk; gate[r1] = g1; trow[tk*2+1] = r1;
  tok[ROWS_ROUTED + tk] = tk; gate[ROWS_ROUTED + tk] = 1.0f;
}

// final combine: out[t] = x[t] + shared_row(t) + routed_row0(t) + routed_row1(t)
__global__ void k_combine(const float* __restrict__ x, const bf16* __restrict__ dbuf,
                          const int* __restrict__ trow, float* __restrict__ out) {
  int tkn = blockIdx.x;
  int t = threadIdx.x;
  int r0 = trow[tkn*2], r1 = trow[tkn*2+1];
  int h = t*4;
  float4 xv = *reinterpret_cast<const float4*>(x + (size_t)tkn*HD + h);
  bf16x4 a = *reinterpret_cast<const bf16x4*>(dbuf + (size_t)(ROWS_ROUTED+tkn)*HD + h);
  bf16x4 b = *reinterpret_cast<const bf16x4*>(dbuf + (size_t)r0*HD + h);
  bf16x4 c = *reinterpret_cast<const bf16x4*>(dbuf + (size_t)r1*HD + h);
  float4 o;
  o.x = xv.x + (float)a[0] + (float)b[0] + (float)c[0];
  o.y = xv.y + (float)a[1] + (float)b[1] + (float)c[1];
  o.z = xv.z + (float)a[2] + (float)b[2] + (float)c[2];
  o.w = xv.w + (float)a[3] + (float)b[3] + (float)c[3];
  *reinterpret_cast<float4*>(out + (size_t)tkn*HD + h) = o;
}

// ---------------- grouped GEMMs: 128x128 tile, BK=32, 4 waves, 2-buffer -------
// (R7/R11 structure — best measured for both GEMMs across 8 structural
// experiments this session.)
// Slot-XOR swizzle via pre-swizzled GLOBAL k-offset; MFMA operands swapped
// (mfma(b,a)) -> packed 8B C-stores. XCD remap for A-strip L2 reuse.

__global__ __launch_bounds__(256,4) void k_gemm_up(
    const bf16* __restrict__ xbf, const bf16* __restrict__ wupT,
    bf16* __restrict__ hbuf, const int* __restrict__ tok,
    const int* __restrict__ meta)
{
  int bx = xcd_remap(blockIdx.x);
  int seg = bx >> 11;           // 64 mt * 32 nt per segment
  int rem = bx & 2047;
  int mt = rem >> 5, nt = rem & 31;   // nt fastest
  int rows = (seg<8)? meta[32+seg] : TOK;
  if (mt*128 >= rows) return;
  int segoff = meta[16+seg];
  int rowbase = mt*128;

  __shared__ __align__(16) bf16 Alds[2][128*32];
  __shared__ __align__(16) bf16 Blds[2][128*32];

  const int t = threadIdx.x;
  const int lane = t & 63, w = t >> 6;

  int lr0 = t>>2, lr1 = 64 + (t>>2);
  int gr0 = rowbase + lr0; if (gr0 >= rows) gr0 = rowbase;
  int gr1 = rowbase + lr1; if (gr1 >= rows) gr1 = rowbase;
  int tok0 = tok[segoff + gr0], tok1 = tok[segoff + gr1];
  int kswz = ((t&3) ^ ((t>>3)&3)) * 8;
  const bf16* gA0 = xbf + (size_t)tok0*HD + kswz;
  const bf16* gA1 = xbf + (size_t)tok1*HD + kswz;
  const bf16* wb = wupT + (size_t)seg*FF*HD;
  int f0 = nt*128;
  const bf16* gB0 = wb + (size_t)(f0 + lr0)*HD + kswz;
  const bf16* gB1 = wb + (size_t)(f0 + lr1)*HD + kswz;

  char* AldsB = (char*)Alds; char* BldsB = (char*)Blds;
  const int stoff = w*1024;

  const int slotb = ((lane>>4) ^ (((lane&15)>>1)&3)) * 16;
  const int Afo = ((w>>1)*64 + (lane&15))*64 + slotb;
  const int Bfo = ((w&1)*64 + (lane&15))*64 + slotb;

  f32x4 acc[4][4] = {};

  stage16(gA0, AldsB + stoff);
  stage16(gA1, AldsB + 4096 + stoff);
  stage16(gB0, BldsB + stoff);
  stage16(gB1, BldsB + 4096 + stoff);
  __syncthreads();

  int cur = 0;
  for (int k0=32; k0<HD; k0+=32) {
    char* an = AldsB + (cur^1)*8192;
    char* bn = BldsB + (cur^1)*8192;
    stage16(gA0 + k0, an + stoff);
    stage16(gA1 + k0, an + 4096 + stoff);
    stage16(gB0 + k0, bn + stoff);
    stage16(gB1 + k0, bn + 4096 + stoff);
    const char* Ab = AldsB + cur*8192 + Afo;
    const char* Bb = BldsB + cur*8192 + Bfo;
    bf16x8 af[4], bfr[4];
    #pragma unroll
    for (int m=0;m<4;m++) af[m]  = *reinterpret_cast<const bf16x8*>(Ab + m*1024);
    #pragma unroll
    for (int n=0;n<4;n++) bfr[n] = *reinterpret_cast<const bf16x8*>(Bb + n*1024);
    #pragma unroll
    for (int m=0;m<4;m++)
      #pragma unroll
      for (int n=0;n<4;n++)
        acc[m][n] = __builtin_amdgcn_mfma_f32_16x16x32_bf16(bfr[n], af[m], acc[m][n], 0,0,0);
    __syncthreads();
    cur ^= 1;
  }
  {
    const char* Ab = AldsB + cur*8192 + Afo;
    const char* Bb = BldsB + cur*8192 + Bfo;
    bf16x8 af[4], bfr[4];
    #pragma unroll
    for (int m=0;m<4;m++) af[m]  = *reinterpret_cast<const bf16x8*>(Ab + m*1024);
    #pragma unroll
    for (int n=0;n<4;n++) bfr[n] = *reinterpret_cast<const bf16x8*>(Bb + n*1024);
    #pragma unroll
    for (int m=0;m<4;m++)
      #pragma unroll
      for (int n=0;n<4;n++)
        acc[m][n] = __builtin_amdgcn_mfma_f32_16x16x32_bf16(bfr[n], af[m], acc[m][n], 0,0,0);
  }

  // epilogue: fast gelu -> packed 8B stores
  const int lrm = lane&15, lq = lane>>4;
  #pragma unroll
  for (int m=0;m<4;m++) {
    int rl = (w>>1)*64 + m*16 + lrm;
    int gr = rowbase + rl;
    if (gr >= rows) continue;
    bf16* hrow = hbuf + (size_t)(segoff+gr)*FF + nt*128 + (w&1)*64 + lq*4;
    #pragma unroll
    for (int n=0;n<4;n++) {
      bf16x4 u;
      #pragma unroll
      for (int j=0;j<4;j++) u[j] = (bf16)fast_gelu(acc[m][n][j]);
      *reinterpret_cast<bf16x4*>(hrow + n*16) = u;
    }
  }
}

__global__ __launch_bounds__(256,4) void k_gemm_down(
    const bf16* __restrict__ hbuf, const bf16* __restrict__ wdnT,
    bf16* __restrict__ dbuf, const float* __restrict__ gate,
    const int* __restrict__ meta)
{
  int bx = xcd_remap(blockIdx.x);
  int seg = bx >> 9;            // 64 mt * 8 nt per segment
  int rem = bx & 511;
  int mt = rem >> 3, nt = rem & 7;   // nt fastest
  int rows = (seg<8)? meta[32+seg] : TOK;
  if (mt*128 >= rows) return;
  int segoff = meta[16+seg];
  int rowbase = mt*128;

  __shared__ __align__(16) bf16 Alds[2][128*32];
  __shared__ __align__(16) bf16 Blds[2][128*32];
  __shared__ float gateL[128];

  const int t = threadIdx.x;
  const int lane = t & 63, w = t >> 6;

  if (t < 128) {
    int gr = rowbase + t; if (gr >= rows) gr = rows - 1;
    gateL[t] = gate[segoff + gr];
  }

  int lr0 = t>>2, lr1 = 64 + (t>>2);
  int kswz = ((t&3) ^ ((t>>3)&3)) * 8;
  const bf16* gA0 = hbuf + (size_t)(segoff + rowbase + lr0)*FF + kswz;
  const bf16* gA1 = hbuf + (size_t)(segoff + rowbase + lr1)*FF + kswz;
  const bf16* wb = wdnT + (size_t)seg*HD*FF;
  int h0 = nt*128;
  const bf16* gB0 = wb + (size_t)(h0 + lr0)*FF + kswz;
  const bf16* gB1 = wb + (size_t)(h0 + lr1)*FF + kswz;

  char* AldsB = (char*)Alds; char* BldsB = (char*)Blds;
  const int stoff = w*1024;

  const int slotb = ((lane>>4) ^ (((lane&15)>>1)&3)) * 16;
  const int Afo = ((w>>1)*64 + (lane&15))*64 + slotb;
  const int Bfo = ((w&1)*64 + (lane&15))*64 + slotb;

  f32x4 acc[4][4] = {};

  stage16(gA0, AldsB + stoff);
  stage16(gA1, AldsB + 4096 + stoff);
  stage16(gB0, BldsB + stoff);
  stage16(gB1, BldsB + 4096 + stoff);
  __syncthreads();

  int cur = 0;
  for (int k0=32; k0<FF; k0+=32) {
    char* an = AldsB + (cur^1)*8192;
    char* bn = BldsB + (cur^1)*8192;
    stage16(gA0 + k0, an + stoff);
    stage16(gA1 + k0, an + 4096 + stoff);
    stage16(gB0 + k0, bn + stoff);
    stage16(gB1 + k0, bn + 4096 + stoff);
    const char* Ab = AldsB + cur*8192 + Afo;
    const char* Bb = BldsB + cur*8192 + Bfo;
    bf16x8 af[4], bfr[4];
    #pragma unroll
    for (int m=0;m<4;m++) af[m]  = *reinterpret_cast<const bf16x8*>(Ab + m*1024);
    #pragma unroll
    for (int n=0;n<4;n++) bfr[n] = *reinterpret_cast<const bf16x8*>(Bb + n*1024);
    #pragma unroll
    for (int m=0;m<4;m++)
      #pragma unroll
      for (int n=0;n<4;n++)
        acc[m][n] = __builtin_amdgcn_mfma_f32_16x16x32_bf16(bfr[n], af[m], acc[m][n], 0,0,0);
    __syncthreads();
    cur ^= 1;
  }
  {
    const char* Ab = AldsB + cur*8192 + Afo;
    const char* Bb = BldsB + cur*8192 + Bfo;
    bf16x8 af[4], bfr[4];
    #pragma unroll
    for (int m=0;m<4;m++) af[m]  = *reinterpret_cast<const bf16x8*>(Ab + m*1024);
    #pragma unroll
    for (int n=0;n<4;n++) bfr[n] = *reinterpret_cast<const bf16x8*>(Bb + n*1024);
    #pragma unroll
    for (int m=0;m<4;m++)
      #pragma unroll
      for (int n=0;n<4;n++)
        acc[m][n] = __builtin_amdgcn_mfma_f32_16x16x32_bf16(bfr[n], af[m], acc[m][n], 0,0,0);
  }

  // epilogue: gate * val -> dbuf rows (bf16, 8B packed)
  const int lrm = lane&15, lq = lane>>4;
  #pragma unroll
  for (int m=0;m<4;m++) {
    int rl = (w>>1)*64 + m*16 + lrm;
    int gr = rowbase + rl;
    if (gr >= rows) continue;
    float g = gateL[rl];
    bf16* drow = dbuf + (size_t)(segoff+gr)*HD + nt*128 + (w&1)*64 + lq*4;
    #pragma unroll
    for (int n=0;n<4;n++) {
      bf16x4 u;
      #pragma unroll
      for (int j=0;j<4;j++) u[j] = (bf16)(acc[m][n][j]*g);
      *reinterpret_cast<bf16x4*>(drow + n*16) = u;
    }
  }
}

// ---------------- host ----------------
struct Layout {
  size_t xbf, wupT, wdnT, hbuf, dbuf, tok, gate, trow, rtE, rtG, meta, total;
};

static inline Layout make_layout() {
  Layout L; size_t o = 0;
  auto al = [&](size_t b){ o = (o+255)&~(size_t)255; size_t r=o; o+=b; return r; };
  L.xbf  = al((size_t)TOK*HD*2);
  L.wupT = al((size_t)NSEG*FF*HD*2);
  L.wdnT = al((size_t)NSEG*FF*HD*2);
  L.hbuf = al((size_t)ROWS_TOT*FF*2);
  L.dbuf = al((size_t)ROWS_TOT*HD*2);
  L.tok  = al((size_t)ROWS_TOT*4);
  L.gate = al((size_t)ROWS_TOT*4);
  L.trow = al((size_t)TOK*2*4);
  L.rtE  = al((size_t)TOK*2*4);
  L.rtG  = al((size_t)TOK*2*4);
  L.meta = al(256*4);
  L.total = o;
  return L;
}

extern "C" void kernel_launch(void* const* d_in, const int* in_sizes, int n_in,
                              void* d_out, int out_size, void* d_ws, size_t ws_size,
                              hipStream_t stream) {
  const float* x           = (const float*)d_in[0];
  const float* shared_up   = (const float*)d_in[1];
  const float* shared_down = (const float*)d_in[2];
  const float* routed_up   = (const float*)d_in[3];
  const float* routed_down = (const float*)d_in[4];
  const float* router_w    = (const float*)d_in[5];
  float* out = (float*)d_out;

  Layout L = make_layout();
  char* ws = (char*)d_ws;
  bf16*  xbf  = (bf16*)(ws + L.xbf);
  bf16*  wupT = (bf16*)(ws + L.wupT);
  bf16*  wdnT = (bf16*)(ws + L.wdnT);
  bf16*  hbuf = (bf16*)(ws + L.hbuf);
  bf16*  dbuf = (bf16*)(ws + L.dbuf);
  int*   tok  = (int*)(ws + L.tok);
  float* gate = (float*)(ws + L.gate);
  int*   trow = (int*)(ws + L.trow);
  int*   rtE  = (int*)(ws + L.rtE);
  float* rtG  = (float*)(ws + L.rtG);
  int*   meta = (int*)(ws + L.meta);

  hipMemsetAsync(meta, 0, 256*4, stream);
  k_tcvt<<<dim3(64, 16, 18), 256, 0, stream>>>(routed_up, shared_up, routed_down, shared_down, wupT, wdnT);
  k_router<<<TOK/4, 256, 0, stream>>>(x, router_w, xbf, rtE, rtG, meta);
  k_scatter<<<TOK/256, 256, 0, stream>>>(rtE, rtG, meta, tok, gate, trow);

  k_gemm_up<<<NSEG*64*32, 256, 0, stream>>>(xbf, wupT, hbuf, tok, meta);      // 18432 blocks
  k_gemm_down<<<NSEG*64*8, 256, 0, stream>>>(hbuf, wdnT, dbuf, gate, meta);   // 4608 blocks
  k_combine<<<TOK, 256, 0, stream>>>(x, dbuf, trow, out);
}